// Round 7
// baseline (104.249 us; speedup 1.0000x reference)
//
#include <hip/hip_runtime.h>

#define N 1024
#define E 256
#define H 128

typedef _Float16 hv2 __attribute__((ext_vector_type(2)));
typedef _Float16 half_t;

__device__ __forceinline__ float dot2_acc(hv2 a, hv2 b, float c) {
#if __has_builtin(__builtin_amdgcn_fdot2)
    return __builtin_amdgcn_fdot2(a, b, c, false);
#else
    return c + (float)a.x * (float)b.x + (float)a.y * (float)b.y;
#endif
}

__device__ __forceinline__ hv2 relu_add2(hv2 a, hv2 b) {
    hv2 s = a + b;
    hv2 z = (hv2)(_Float16)0.f;
    return __builtin_elementwise_max(s, z);
}

// proj (unfolded, self-contained): 4 rows per block, 256 blocks.
// Per block: recompute ctx = relu(x@Wc+bc) (~128 MAC/thr, redundant but cheap),
// s_i = P_i@W{q,k} + b{q,k} + ctx (4 rows share each W column load -> halves
// the dominant per-block weight traffic vs 2-row round-5: 262MB -> 131MB L2),
// qp_i = s_i@W1a + b1 / kp_i = s_i@W1b, written as f16.
// Threads 0..127 = q-side (h=t), 128..255 = k-side (h=t-128).
__global__ __launch_bounds__(256) void proj_kernel(
    const float* __restrict__ x, const float* __restrict__ P,
    const float* __restrict__ Wq, const float* __restrict__ bq,
    const float* __restrict__ Wk, const float* __restrict__ bk,
    const float* __restrict__ Wc, const float* __restrict__ bc,
    const float* __restrict__ W1, const float* __restrict__ b1,
    half_t* __restrict__ qh, half_t* __restrict__ kh) {
    __shared__ __align__(16) float xs[E];        // next-state embedding
    __shared__ __align__(16) float p_s[4 * E];   // 4 P rows
    __shared__ float pc[2 * H];                  // ctx partials
    __shared__ float aq[H], ak[H];               // bq+ctx, bk+ctx
    __shared__ float sv[4][2 * H];               // s vectors: [row][q | k]

    int b = blockIdx.x, t = threadIdx.x;
    int i0 = b * 4;
    if (t < 64) ((float4*)xs)[t] = ((const float4*)x)[t];
    ((float4*)p_s)[t] = ((const float4*)(P + i0 * E))[t];  // 256 f4 = 4 rows
    __syncthreads();

    int h = t & (H - 1);
    int c = t >> 7;  // 0 = q-side, 1 = k-side

    // ctx partials: side c covers e in [c*128, c*128+128)
    {
        float p = 0.f;
#pragma unroll 8
        for (int e = c * H; e < c * H + H; ++e) p += xs[e] * Wc[e * H + h];
        pc[c * H + h] = p;
    }
    __syncthreads();
    if (t < H) {
        float ctxv = fmaxf(pc[t] + pc[H + t] + bc[t], 0.f);
        aq[t] = bq[t] + ctxv;
        ak[t] = bk[t] + ctxv;
    }
    __syncthreads();

    // s_i = P_i @ W + (b + ctx); 4 rows share each W column load
    {
        const float* W = c ? Wk : Wq;
        float base = c ? ak[h] : aq[h];
        float a0 = base, a1 = base, a2 = base, a3 = base;
        for (int e = 0; e < E; e += 8) {
            float m0 = W[(e + 0) * H + h];
            float m1 = W[(e + 1) * H + h];
            float m2 = W[(e + 2) * H + h];
            float m3 = W[(e + 3) * H + h];
            float m4 = W[(e + 4) * H + h];
            float m5 = W[(e + 5) * H + h];
            float m6 = W[(e + 6) * H + h];
            float m7 = W[(e + 7) * H + h];
            float4 pa, pb;
            pa = *(const float4*)&p_s[0 * E + e];
            pb = *(const float4*)&p_s[0 * E + e + 4];
            a0 += pa.x * m0 + pa.y * m1 + pa.z * m2 + pa.w * m3
                + pb.x * m4 + pb.y * m5 + pb.z * m6 + pb.w * m7;
            pa = *(const float4*)&p_s[1 * E + e];
            pb = *(const float4*)&p_s[1 * E + e + 4];
            a1 += pa.x * m0 + pa.y * m1 + pa.z * m2 + pa.w * m3
                + pb.x * m4 + pb.y * m5 + pb.z * m6 + pb.w * m7;
            pa = *(const float4*)&p_s[2 * E + e];
            pb = *(const float4*)&p_s[2 * E + e + 4];
            a2 += pa.x * m0 + pa.y * m1 + pa.z * m2 + pa.w * m3
                + pb.x * m4 + pb.y * m5 + pb.z * m6 + pb.w * m7;
            pa = *(const float4*)&p_s[3 * E + e];
            pb = *(const float4*)&p_s[3 * E + e + 4];
            a3 += pa.x * m0 + pa.y * m1 + pa.z * m2 + pa.w * m3
                + pb.x * m4 + pb.y * m5 + pb.z * m6 + pb.w * m7;
        }
        sv[0][c * H + h] = a0;
        sv[1][c * H + h] = a1;
        sv[2][c * H + h] = a2;
        sv[3][c * H + h] = a3;
    }
    __syncthreads();

    // qp_i = s_i @ W1a + b1 (q-side) ; kp_i = s_i @ W1b (k-side).
    // sv reads are wave-broadcast (same addr across lanes).
    {
        const float* W1c = W1 + c * H * H;
        const float* S0 = &sv[0][c * H];
        const float* S1 = &sv[1][c * H];
        const float* S2 = &sv[2][c * H];
        const float* S3 = &sv[3][c * H];
        float bb = c ? 0.f : b1[h];
        float a0 = bb, a1 = bb, a2 = bb, a3 = bb;
        for (int r = 0; r < H; r += 4) {
            float w0 = W1c[(r + 0) * H + h];
            float w1 = W1c[(r + 1) * H + h];
            float w2 = W1c[(r + 2) * H + h];
            float w3 = W1c[(r + 3) * H + h];
            a0 += S0[r] * w0 + S0[r + 1] * w1 + S0[r + 2] * w2 + S0[r + 3] * w3;
            a1 += S1[r] * w0 + S1[r + 1] * w1 + S1[r + 2] * w2 + S1[r + 3] * w3;
            a2 += S2[r] * w0 + S2[r + 1] * w1 + S2[r + 2] * w2 + S2[r + 3] * w3;
            a3 += S3[r] * w0 + S3[r + 1] * w1 + S3[r + 2] * w2 + S3[r + 3] * w3;
        }
        half_t* O = c ? kh : qh;
        O[(i0 + 0) * H + h] = (half_t)a0;
        O[(i0 + 1) * H + h] = (half_t)a1;
        O[(i0 + 2) * H + h] = (half_t)a2;
        O[(i0 + 3) * H + h] = (half_t)a3;
    }
}

// pair: exact triangular tiling. 528 blocks, one 32x32 (bi<=bj) tile each.
// Per thread: 4 (i,j) pairs; f16 LDS + fdot2. (Unchanged, harness-verified.)
#define QSTR 136  // halves; 272 B row stride -> conflict-free b128
__global__ __launch_bounds__(256) void pair_kernel(
    const half_t* __restrict__ qh, const half_t* __restrict__ kh,
    const float* __restrict__ W2, const float* __restrict__ b2,
    float* __restrict__ out) {
    int tid = blockIdx.x;
    int bi = (int)((65.0f - sqrtf(4225.0f - 8.0f * (float)tid)) * 0.5f);
    while (bi > 0 && tid < 32 * bi - bi * (bi - 1) / 2) --bi;
    while (tid >= 32 * (bi + 1) - (bi + 1) * bi / 2) ++bi;
    int bj = bi + (tid - (32 * bi - bi * (bi - 1) / 2));

    __shared__ __align__(16) half_t qs[32][QSTR];
    __shared__ __align__(16) half_t ks[32][QSTR];
    __shared__ __align__(16) half_t w2s[H];

    int t = threadIdx.x;
    if (t < H) w2s[t] = (half_t)W2[t];

    const float4* qh4 = (const float4*)(qh + bi * 32 * H);
    const float4* kh4 = (const float4*)(kh + bj * 32 * H);
#pragma unroll
    for (int v = 0; v < 2; ++v) {
        int idx = v * 256 + t;  // 0..511 : 32 rows x 16 float4
        int r = idx >> 4, c = idx & 15;
        float4 q = qh4[idx];
        float4 k = kh4[idx];
        *(float4*)&qs[r][c * 8] = q;
        *(float4*)&ks[r][c * 8] = k;
    }
    __syncthreads();

    int jj  = t & 31;  // k row within tile
    int ti0 = t >> 5;  // q rows ti0, ti0+8, ti0+16, ti0+24
    float b2v = b2[0];
    float acc[4];
#pragma unroll
    for (int u = 0; u < 4; ++u) acc[u] = b2v;

    for (int h8 = 0; h8 < 16; ++h8) {
        float4 wf = *(const float4*)&w2s[h8 * 8];
        float4 kv = *(const float4*)&ks[jj][h8 * 8];
        const hv2* wp = (const hv2*)&wf;
        const hv2* kp2 = (const hv2*)&kv;
#pragma unroll
        for (int u = 0; u < 4; ++u) {
            float4 qf = *(const float4*)&qs[ti0 + u * 8][h8 * 8];
            const hv2* qp2 = (const hv2*)&qf;
#pragma unroll
            for (int s = 0; s < 4; ++s) {
                hv2 sa = relu_add2(qp2[s], kp2[s]);
                acc[u] = dot2_acc(sa, wp[s], acc[u]);
            }
        }
    }

#pragma unroll
    for (int u = 0; u < 4; ++u) {
        int i = bi * 32 + ti0 + u * 8;
        int j = bj * 32 + jj;
        if (j > i) {
            int base = i * (2 * N - i - 1) / 2;
            out[base + (j - i - 1)] = acc[u];
        }
    }
}

extern "C" void kernel_launch(void* const* d_in, const int* in_sizes, int n_in,
                              void* d_out, int out_size, void* d_ws, size_t ws_size,
                              hipStream_t stream) {
    const float* x  = (const float*)d_in[0];
    const float* P  = (const float*)d_in[1];
    const float* Wq = (const float*)d_in[2];
    const float* bq = (const float*)d_in[3];
    const float* Wk = (const float*)d_in[4];
    const float* bk = (const float*)d_in[5];
    const float* Wc = (const float*)d_in[6];
    const float* bc = (const float*)d_in[7];
    const float* W1 = (const float*)d_in[8];
    const float* b1 = (const float*)d_in[9];
    const float* W2 = (const float*)d_in[10];
    const float* b2 = (const float*)d_in[11];
    float* out = (float*)d_out;

    half_t* qh = (half_t*)d_ws;        // 1024*128 halves
    half_t* kh = qh + N * H;           // 1024*128 halves

    proj_kernel<<<N / 4, 256, 0, stream>>>(x, P, Wq, bq, Wk, bk, Wc, bc, W1, b1,
                                           qh, kh);
    pair_kernel<<<528, 256, 0, stream>>>(qh, kh, W2, b2, out);
}